// Round 13
// baseline (678.703 us; speedup 1.0000x reference)
//
#include <hip/hip_runtime.h>
#include <stdint.h>

// DCGRU cell on MI355X — round 13: r12 + gemm LDS exactly 32KB (5 blocks/CU,
// two-pass 64-col epilogue) + counted-vmcnt in proj K-loop.
//
// Buffers (d_ws, ~161 MB):
//   Abf8 [4096][2048] u8    supports stacked [A0;A1] x512 (e4m3)
//   Xbf  [4224][2048] bf16  X rows (b*66+c); rows 2..65 overwritten r*hx
//   Xf8  [4224][2048] u8    X in e4m3 (same row layout)
//   Y1f8 [4224][4096] u8    x1 (both supports) x32 (e4m3)
//   Ht   [131072][352] bf16 packed H^T: row m=(b*2048+n), col K = slot*66+c
//   Ubuf [64*64*2048] bf16  u gate
//   Wt_ru/Wt_c [128][352] bf16

typedef unsigned short ushort_t;
typedef __attribute__((ext_vector_type(8))) __bf16 bf16x8;
typedef __attribute__((ext_vector_type(4))) float f32x4;
typedef __attribute__((ext_vector_type(16))) float f32x16;
typedef __attribute__((ext_vector_type(8))) int i32x8;

#define KP 352
#define MROWS 131072

__device__ __forceinline__ ushort_t f2bf(float f) {
  union { float f; uint32_t u; } v; v.f = f;
  uint32_t r = v.u + 0x7FFFu + ((v.u >> 16) & 1u);   // RNE
  return (ushort_t)(r >> 16);
}
__device__ __forceinline__ float bf2f(ushort_t u) {
  union { uint32_t u; float f; } v; v.u = ((uint32_t)u) << 16;
  return v.f;
}

__device__ __forceinline__ void gl_lds16(const void* g, void* l) {
  __builtin_amdgcn_global_load_lds(
      (const __attribute__((address_space(1))) void*)g,
      (__attribute__((address_space(3))) void*)l, 16, 0, 0);
}

// ---------------- prep kernels ----------------

__global__ void k_cast_f8(const float* __restrict__ src, uint32_t* __restrict__ dst,
                          int n4, float scale) {
  for (int i = blockIdx.x * 256 + threadIdx.x; i < n4; i += gridDim.x * 256) {
    float4 v = ((const float4*)src)[i];
    int r = __builtin_amdgcn_cvt_pk_fp8_f32(v.x * scale, v.y * scale, 0, 0);
    r = __builtin_amdgcn_cvt_pk_fp8_f32(v.z * scale, v.w * scale, r, 1);
    dst[i] = (uint32_t)r;
  }
}

__global__ void k_build_X(const float* __restrict__ inputs, const float* __restrict__ hx,
                          ushort_t* __restrict__ Xbf, uint8_t* __restrict__ Xf8) {
  int r = blockIdx.x;
  int b = r / 66, c = r - b * 66;
  const float* src = (c < 2) ? (inputs + ((size_t)b * 2 + c) * 2048)
                             : (hx + ((size_t)b * 64 + (c - 2)) * 2048);
  ushort_t* d1 = Xbf + (size_t)r * 2048;
  uint8_t* d2 = Xf8 + (size_t)r * 2048;
  for (int n = threadIdx.x * 4; n < 2048; n += 256 * 4) {
    float4 v = *(const float4*)(src + n);
    ushort4 rr;
    rr.x = f2bf(v.x); rr.y = f2bf(v.y); rr.z = f2bf(v.z); rr.w = f2bf(v.w);
    *(ushort4*)(d1 + n) = rr;
    int r8 = __builtin_amdgcn_cvt_pk_fp8_f32(v.x, v.y, 0, 0);
    r8 = __builtin_amdgcn_cvt_pk_fp8_f32(v.z, v.w, r8, 1);
    *(uint32_t*)(d2 + n) = (uint32_t)r8;
  }
}

__global__ void k_pack_W(const float* __restrict__ Wru, const float* __restrict__ Wc,
                         ushort_t* __restrict__ Wtru, ushort_t* __restrict__ Wtc) {
  int o = blockIdx.x;
  const float* W = (o < 128) ? Wru : Wc;
  int O = (o < 128) ? 128 : 64;
  int oo = (o < 128) ? o : (o - 128);
  ushort_t* Wt = (o < 128) ? Wtru : Wtc;
  for (int k = threadIdx.x; k < KP; k += 256) {
    float v = (k < 330 && oo < O) ? W[(size_t)k * O + oo] : 0.f;
    Wt[(size_t)oo * KP + k] = f2bf(v);
  }
}

// Ht[(b*2048+n)][0..66) = Xbf[(b*66+c)][n]. grid (16, 64) — conv1 only
__global__ __launch_bounds__(256) void k_trans_slot0(const ushort_t* __restrict__ Xbf,
                                                     ushort_t* __restrict__ Ht) {
  __shared__ ushort_t t[66 * 136];
  const int tid = threadIdx.x;
  const int b = blockIdx.y;
  const int n0 = blockIdx.x * 128;
  for (int idx = tid; idx < 66 * 16; idx += 256) {
    int c = idx >> 4, seg = idx & 15;
    bf16x8 v = *(const bf16x8*)&Xbf[((size_t)b * 66 + c) * 2048 + n0 + seg * 8];
    *(bf16x8*)&t[c * 136 + seg * 8] = v;
  }
  __syncthreads();
  for (int idx = tid; idx < 128 * 33; idx += 256) {
    int nn = idx / 33, pc = idx - nn * 33;
    int c = pc * 2;
    uint32_t pk = (uint32_t)t[c * 136 + nn] | ((uint32_t)t[(c + 1) * 136 + nn] << 16);
    *(uint32_t*)&Ht[((size_t)b * 2048 + n0 + nn) * KP + c] = pk;
  }
}

// ---------------- MX-fp8 diffusion GEMM (BK=64, counted-vmcnt dbuf) ----------------
// C[r,m] = sum_k A[r,k]*B[m,k] over K=2048 (32 tiles of BK=64).
// LDS exactly 32768 B (2x16KB dbuf; epilogue cTile 64x130 ushort reuses it)
// -> 5 blocks/CU (160KiB/32KiB), 20 waves/CU; per-XCD residency 160 >= 132
// blocks -> single A sweep. Two-pass epilogue over 64-col halves (r4 pattern).
// MODE 0: A=Xf8 (scale 1), writes Ht slot (1+2g) bf16 + Y1f8 = fp8(32*v).
// MODE 1: A=Y1f8+g*2048 (scale 2^-5), Ht slot (2+2g) = bf16(2v - Xres).
// B always Abf8 (scale 2^-9).
template <int MODE>
__global__ __launch_bounds__(256, 5) void gemm_bt(
    const uint8_t* __restrict__ Aop, int lda,
    const uint8_t* __restrict__ Bop,
    const ushort_t* __restrict__ Xres,
    uint8_t* __restrict__ Y1f8,
    ushort_t* __restrict__ Ht) {
  __shared__ char smem[32768];   // dbuf 2x16KB; epilogue cTile 64x130 ushort
  ushort_t* smemU = (ushort_t*)smem;
  const int tid = threadIdx.x;
  const int l = tid & 63, w = tid >> 6;
  const int wr = w >> 1, wc = w & 1;
  const int rowL = l & 31;
  const int kh = l >> 5;
  const int m7 = (rowL >> 2) & 7;

  // XCD-aware bijective remap (1056 = 8 * 132; 132 = 4 nb * 33 mb)
  const int fid = blockIdx.y * 33 + blockIdx.x;
  const int xcd = fid & 7;
  const int idx = fid >> 3;
  const int nb = xcd * 4 + idx / 33;
  const int mb = idx % 33;
  const int r0 = mb * 128;
  const int m0 = nb * 128;
  const int g = m0 >> 11;
  if (MODE == 1) Aop += (size_t)g * 2048;

  const int SA = (MODE == 0) ? 0x7F7F7F7F : 0x7A7A7A7A;  // 1.0 / 2^-5
  const int SB = 0x76767676;                             // 2^-9

  f32x16 acc[2][2];
#pragma unroll
  for (int mi = 0; mi < 2; ++mi)
#pragma unroll
    for (int ni = 0; ni < 2; ++ni)
#pragma unroll
      for (int q = 0; q < 16; ++q) acc[mi][ni][q] = 0.f;

  const int d = tid;
  const int srow = ((d >> 3) << 2) | (((d >> 1) ^ (d >> 4)) & 1) |
                   ((((d >> 2) ^ (d >> 5)) & 1) << 1);
  const int sj = (d ^ (d >> 3)) & 1;
  const uint8_t* pA = Aop + (size_t)(r0 + srow) * lda + sj * 16;
  const uint8_t* pB = Bop + (size_t)(m0 + srow) * 2048 + sj * 16;

  const int sj0 = ((rowL * 2) ^ m7) * 16;
  const int sj1 = ((rowL * 2 + 1) ^ m7) * 16;
  const int aw = wr * 2048;
  const int bw = wc * 2048;

#define STAGEF(TT, BB)                                                       \
  {                                                                          \
    const int kb_ = (TT) * 64;                                               \
    gl_lds16(pA + kb_,      smem + (BB) + tid * 16);                         \
    gl_lds16(pA + kb_ + 32, smem + (BB) + 4096 + tid * 16);                  \
    gl_lds16(pB + kb_,      smem + (BB) + 8192 + tid * 16);                  \
    gl_lds16(pB + kb_ + 32, smem + (BB) + 8192 + 4096 + tid * 16);           \
  }

#define COMPUTEF(BB)                                                         \
  {                                                                          \
    const int rbase = kh * 4096;                                             \
    union { uint4 q[2]; i32x8 v; } bu[2], au;                                \
    _Pragma("unroll")                                                        \
    for (int ni = 0; ni < 2; ++ni) {                                         \
      const char* bp = smem + (BB) + 8192 + rbase + bw + ni * 1024;          \
      bu[ni].q[0] = *(const uint4*)(bp + sj0);                               \
      bu[ni].q[1] = *(const uint4*)(bp + sj1);                               \
    }                                                                        \
    _Pragma("unroll")                                                        \
    for (int mi = 0; mi < 2; ++mi) {                                         \
      const char* ap = smem + (BB) + rbase + aw + mi * 1024;                 \
      au.q[0] = *(const uint4*)(ap + sj0);                                   \
      au.q[1] = *(const uint4*)(ap + sj1);                                   \
      _Pragma("unroll")                                                      \
      for (int ni = 0; ni < 2; ++ni)                                         \
        acc[mi][ni] = __builtin_amdgcn_mfma_scale_f32_32x32x64_f8f6f4(       \
            au.v, bu[ni].v, acc[mi][ni], 0, 0, 0, SA, 0, SB);                \
    }                                                                        \
  }

  const int kt0 = (idx & 3) * 8;
  STAGEF(kt0, 0);
#pragma unroll 1
  for (int ktt = 0; ktt < 32; ++ktt) {
    const int cur = (ktt & 1) * 16384;
    if (ktt + 1 < 32) {
      STAGEF(((ktt + 1 + kt0) & 31), cur ^ 16384);
      asm volatile("s_waitcnt vmcnt(4)" ::: "memory");
    } else {
      asm volatile("s_waitcnt vmcnt(0)" ::: "memory");
    }
    __builtin_amdgcn_s_barrier();
    __builtin_amdgcn_sched_barrier(0);
    COMPUTEF(cur);
    __builtin_amdgcn_s_barrier();   // raw: protect next overwrite (no drain)
  }

#undef STAGEF
#undef COMPUTEF

  // ---------------- two-pass epilogue (64-col halves; r4 pattern) ----------
  // C layout (32x32): col = lane&31, row = (q&3) + 8*(q>>2) + 4*(lane>>5)
  const int slotBase = (MODE == 0 ? 1 : 2) + 2 * g;
  const int n_base = m0 & 2047;

#pragma unroll 1
  for (int pass = 0; pass < 2; ++pass) {
    __syncthreads();
    if (wc == pass) {
#pragma unroll
      for (int mi = 0; mi < 2; ++mi) {
#pragma unroll
        for (int ni = 0; ni < 2; ++ni) {
          const int clb = ni * 32 + rowL;        // 0..63 within this half
#pragma unroll
          for (int q = 0; q < 16; ++q) {
            const int rl = wr * 64 + mi * 32 + (q & 3) + 8 * (q >> 2) + 4 * kh;
            float v = acc[mi][ni][q];
            if (MODE == 1)
              v = 2.f * v -
                  bf2f(Xres[(size_t)(r0 + rl) * 2048 + ((m0 + pass * 64 + clb) & 2047)]);
            smemU[clb * 130 + rl] = f2bf(v);
          }
        }
      }
    }
    __syncthreads();

    // Ht store, dword-packed (pairs (rl, rl+1) same b, even c)
#pragma unroll 2
    for (int j2 = 0; j2 < 16; ++j2) {
      int idx2 = j2 * 256 + tid;
      int mc = idx2 >> 6, pr = idx2 & 63;
      int rl = pr * 2;
      unsigned rg = (unsigned)(r0 + rl);
      unsigned b = rg / 66u;
      unsigned c = rg - b * 66u;        // even
      int n = n_base + pass * 64 + mc;
      uint32_t pk = (uint32_t)smemU[mc * 130 + rl] |
                    ((uint32_t)smemU[mc * 130 + rl + 1] << 16);
      *(uint32_t*)&Ht[((size_t)b * 2048 + n) * KP + slotBase * 66 + c] = pk;
    }

    // Y1f8 pass (MODE 0): fp8(32*v), dword-packed, coalesced
    if (MODE == 0) {
#pragma unroll 2
      for (int it = 0; it < 8; ++it) {
        int idx2 = it * 256 + tid;
        int rl = idx2 >> 4, mq = idx2 & 15;
        float v0 = bf2f(smemU[(mq * 4 + 0) * 130 + rl]) * 32.f;
        float v1 = bf2f(smemU[(mq * 4 + 1) * 130 + rl]) * 32.f;
        float v2 = bf2f(smemU[(mq * 4 + 2) * 130 + rl]) * 32.f;
        float v3 = bf2f(smemU[(mq * 4 + 3) * 130 + rl]) * 32.f;
        int r8 = __builtin_amdgcn_cvt_pk_fp8_f32(v0, v1, 0, 0);
        r8 = __builtin_amdgcn_cvt_pk_fp8_f32(v2, v3, r8, 1);
        *(uint32_t*)(Y1f8 + (size_t)(r0 + rl) * 4096 + m0 + pass * 64 + mq * 4) =
            (uint32_t)r8;
      }
    }
  }
}

// ---------------- MFMA projection GEMM (r12 epilogue + counted-vmcnt loop) ----
// MODE 0 (RU): s=sigmoid; Xbf/Xf8 rows 2..65 = r*hx, Ubuf = u, Ht slot0
//              cols 2..65 = bf16(r*hx) transposed.
// MODE 1 (CF): out = u*hx + (1-u)*tanh(...).
template <int MODE>
__global__ __launch_bounds__(256, 4) void proj_mfma(
    const ushort_t* __restrict__ Ht_c, const ushort_t* __restrict__ Wt,
    const float* __restrict__ bias, const float* __restrict__ hx,
    ushort_t* __restrict__ Xbf, uint8_t* __restrict__ Xf8,
    ushort_t* __restrict__ Ubuf, ushort_t* __restrict__ HtW,
    float* __restrict__ out) {
  __shared__ ushort_t smem[16640];
  const int tid = threadIdx.x;
  const int l = tid & 63, w = tid >> 6;
  const int wr = w >> 1, wc = w & 1;
  const int lr = l & 15, lk = l >> 4;
  const int bb = blockIdx.x >> 4;
  const int n0 = (blockIdx.x & 15) * 128;
  const size_t m0 = (size_t)bb * 2048 + n0;

  f32x4 acc[4][4];
  const f32x4 zero = {0.f, 0.f, 0.f, 0.f};
#pragma unroll
  for (int mi = 0; mi < 4; mi++)
#pragma unroll
    for (int ni = 0; ni < 4; ni++) acc[mi][ni] = zero;

  const int srow = tid >> 2;
  const int kcol = ((tid & 3) ^ ((tid >> 3) & 3)) * 8;
  const ushort_t* pA = Ht_c + (m0 + srow) * KP + kcol;
  const ushort_t* pB = Wt + (size_t)srow * KP + kcol;
  const int so = (lk ^ ((lr >> 1) & 3)) * 8;

#define STAGEP(KT, BB)                                                         \
  {                                                                            \
    const int kp_ = (KT) * 32;                                                 \
    gl_lds16(pA + kp_, (void*)&smem[(BB) + tid * 8]);                          \
    gl_lds16(pA + (size_t)64 * KP + kp_, (void*)&smem[(BB) + 2048 + tid * 8]); \
    gl_lds16(pB + kp_, (void*)&smem[(BB) + 4096 + tid * 8]);                   \
    gl_lds16(pB + (size_t)64 * KP + kp_, (void*)&smem[(BB) + 6144 + tid * 8]); \
  }

#define COMPUTEP(BB)                                                           \
  {                                                                            \
    bf16x8 af[4], bfv[4];                                                      \
    _Pragma("unroll")                                                          \
    for (int i = 0; i < 4; i++)                                                \
      af[i] = *(const bf16x8*)&smem[(BB) + (wr * 64 + i * 16 + lr) * 32 + so]; \
    _Pragma("unroll")                                                          \
    for (int i = 0; i < 4; i++)                                                \
      bfv[i] = *(const bf16x8*)&smem[(BB) + 4096 + (wc * 64 + i * 16 + lr) * 32 + so]; \
    _Pragma("unroll")                                                          \
    for (int mi = 0; mi < 4; mi++)                                             \
      _Pragma("unroll")                                                        \
      for (int ni = 0; ni < 4; ni++)                                           \
        acc[mi][ni] = __builtin_amdgcn_mfma_f32_16x16x32_bf16(af[mi], bfv[ni], \
                                                              acc[mi][ni], 0, 0, 0); \
  }

  STAGEP(0, 0);
#pragma unroll 1
  for (int kt = 0; kt < 11; ++kt) {
    if (kt + 1 < 11) {
      STAGEP(kt + 1, ((kt + 1) & 1) * 8192);
      asm volatile("s_waitcnt vmcnt(4)" ::: "memory");
    } else {
      asm volatile("s_waitcnt vmcnt(0)" ::: "memory");
    }
    __builtin_amdgcn_s_barrier();
    __builtin_amdgcn_sched_barrier(0);
    COMPUTEP((kt & 1) * 8192);
    __builtin_amdgcn_s_barrier();
  }

#undef STAGEP
#undef COMPUTEP

  // activation into transposed LDS tile sTile[o][m]
#pragma unroll
  for (int mi = 0; mi < 4; mi++) {
#pragma unroll
    for (int ni = 0; ni < 4; ni++) {
      const int rl0 = wr * 64 + mi * 16 + lk * 4;
      const int o = wc * 64 + ni * 16 + lr;
      float bv = (MODE == 0 || o < 64) ? bias[o] : 0.f;
#pragma unroll
      for (int j = 0; j < 4; j++) {
        float v = acc[mi][ni][j] + bv;
        float s;
        if (MODE == 0) s = 1.f / (1.f + expf(-v));
        else           s = tanhf(v);
        smem[o * 130 + rl0 + j] = f2bf(s);
      }
    }
  }
  __syncthreads();

  if (MODE == 0) {
    // pass 1: o<64 -> smem = r*hx (hx read coalesced); o>=64 -> Ubuf = u
#pragma unroll 4
    for (int j2 = 0; j2 < 64; ++j2) {
      int idx = j2 * 256 + tid;
      int o = idx >> 7, m = idx & 127;
      ushort_t sv = smem[o * 130 + m];
      if (o < 64) {
        float p = bf2f(sv) * hx[((size_t)bb * 64 + o) * 2048 + n0 + m];
        smem[o * 130 + m] = f2bf(p);
      } else {
        Ubuf[((size_t)bb * 64 + (o - 64)) * 2048 + n0 + m] = sv;
      }
    }
    __syncthreads();
    // pass 2: Xbf (ushort4) + Xf8 (dword) rows, coalesced
#pragma unroll 2
    for (int j2 = 0; j2 < 8; ++j2) {
      int idx = j2 * 256 + tid;
      int o = idx >> 5, m4 = (idx & 31) * 4;
      ushort_t s0 = smem[o * 130 + m4 + 0], s1 = smem[o * 130 + m4 + 1];
      ushort_t s2 = smem[o * 130 + m4 + 2], s3 = smem[o * 130 + m4 + 3];
      ushort4 pk4; pk4.x = s0; pk4.y = s1; pk4.z = s2; pk4.w = s3;
      *(ushort4*)&Xbf[((size_t)bb * 66 + 2 + o) * 2048 + n0 + m4] = pk4;
      int r8 = __builtin_amdgcn_cvt_pk_fp8_f32(bf2f(s0), bf2f(s1), 0, 0);
      r8 = __builtin_amdgcn_cvt_pk_fp8_f32(bf2f(s2), bf2f(s3), r8, 1);
      *(uint32_t*)(Xf8 + ((size_t)bb * 66 + 2 + o) * 2048 + n0 + m4) = (uint32_t)r8;
    }
    // pass 3: Ht slot0 cols 2..65 transposed, dword-packed (o even pairs)
#pragma unroll 2
    for (int j2 = 0; j2 < 16; ++j2) {
      int idx = j2 * 256 + tid;
      int m = idx >> 5, po = idx & 31;
      int o = po * 2;
      uint32_t pk = (uint32_t)smem[o * 130 + m] |
                    ((uint32_t)smem[(o + 1) * 130 + m] << 16);
      *(uint32_t*)&HtW[((size_t)bb * 2048 + n0 + m) * KP + 2 + o] = pk;
    }
  } else {
#pragma unroll 4
    for (int j2 = 0; j2 < 32; ++j2) {
      int idx = j2 * 256 + tid;
      int o = idx >> 7, m = idx & 127;
      float Cv = bf2f(smem[o * 130 + m]);
      int n = n0 + m;
      size_t oi = ((size_t)bb * 64 + o) * 2048 + n;
      float u = bf2f(Ubuf[oi]);
      out[oi] = u * hx[oi] + (1.f - u) * Cv;
    }
  }
}

// ---------------- launcher ----------------

extern "C" void kernel_launch(void* const* d_in, const int* in_sizes, int n_in,
                              void* d_out, int out_size, void* d_ws, size_t ws_size,
                              hipStream_t stream) {
  (void)in_sizes; (void)n_in; (void)out_size; (void)ws_size;
  const float* inputs = (const float*)d_in[0];
  const float* hx     = (const float*)d_in[1];
  const float* s0     = (const float*)d_in[2];
  const float* s1     = (const float*)d_in[3];
  const float* W_ru   = (const float*)d_in[4];
  const float* b_ru   = (const float*)d_in[5];
  const float* W_c    = (const float*)d_in[6];
  const float* b_c    = (const float*)d_in[7];
  float* out = (float*)d_out;

  char* p = (char*)d_ws;
  uint8_t*  Abf8 = (uint8_t*)p;  p += (size_t)4096 * 2048;        //  8.39 MB
  ushort_t* Xbf  = (ushort_t*)p; p += (size_t)4224 * 2048 * 2;    // 17.30 MB
  uint8_t*  Xf8  = (uint8_t*)p;  p += (size_t)4224 * 2048;        //  8.65 MB
  uint8_t*  Y1f8 = (uint8_t*)p;  p += (size_t)4224 * 4096;        // 17.30 MB
  ushort_t* Ht   = (ushort_t*)p; p += (size_t)MROWS * KP * 2;     // 92.27 MB
  ushort_t* Ubuf = (ushort_t*)p; p += (size_t)64 * 64 * 2048 * 2; // 16.78 MB
  ushort_t* Wtru = (ushort_t*)p; p += (size_t)128 * KP * 2;       // 90 KB
  ushort_t* Wtc  = (ushort_t*)p; p += (size_t)128 * KP * 2;       // 90 KB

  k_cast_f8<<<1024, 256, 0, stream>>>(s0, (uint32_t*)Abf8, 1048576, 512.f);
  k_cast_f8<<<1024, 256, 0, stream>>>(s1, (uint32_t*)(Abf8 + 4194304), 1048576, 512.f);
  k_build_X<<<4224, 256, 0, stream>>>(inputs, hx, Xbf, Xf8);
  k_pack_W<<<192, 256, 0, stream>>>(W_ru, W_c, Wtru, Wtc);

  dim3 g(33, 32);
  dim3 gt(16, 64);
  // conv 1
  k_trans_slot0<<<gt, 256, 0, stream>>>(Xbf, Ht);
  gemm_bt<0><<<g, 256, 0, stream>>>(Xf8, 2048, Abf8, nullptr, Y1f8, Ht);
  gemm_bt<1><<<g, 256, 0, stream>>>(Y1f8, 4096, Abf8, Xbf, nullptr, Ht);
  proj_mfma<0><<<1024, 256, 0, stream>>>(Ht, Wtru, b_ru, hx, Xbf, Xf8, Ubuf, Ht, nullptr);
  // conv 2 (slot0 cols 0,1 persist; cols 2..65 written by proj_mfma<0>)
  gemm_bt<0><<<g, 256, 0, stream>>>(Xf8, 2048, Abf8, nullptr, Y1f8, Ht);
  gemm_bt<1><<<g, 256, 0, stream>>>(Y1f8, 4096, Abf8, Xbf, nullptr, Ht);
  proj_mfma<1><<<1024, 256, 0, stream>>>(Ht, Wtc, b_c, hx, nullptr, nullptr, Ubuf, nullptr, out);
}

// Round 14
// 411.753 us; speedup vs baseline: 1.6483x; 1.6483x over previous
//
#include <hip/hip_runtime.h>
#include <stdint.h>

// DCGRU cell on MI355X — round 14: r12 gemm (best, 414us) restored verbatim;
// proj_mfma K-loop upgraded to the r12-validated counted-vmcnt gate.
//
// Buffers (d_ws, ~161 MB):
//   Abf8 [4096][2048] u8    supports stacked [A0;A1] x512 (e4m3)
//   Xbf  [4224][2048] bf16  X rows (b*66+c); rows 2..65 overwritten r*hx
//   Xf8  [4224][2048] u8    X in e4m3 (same row layout)
//   Y1f8 [4224][4096] u8    x1 (both supports) x32 (e4m3)
//   Ht   [131072][352] bf16 packed H^T: row m=(b*2048+n), col K = slot*66+c
//   Ubuf [64*64*2048] bf16  u gate
//   Wt_ru/Wt_c [128][352] bf16

typedef unsigned short ushort_t;
typedef __attribute__((ext_vector_type(8))) __bf16 bf16x8;
typedef __attribute__((ext_vector_type(4))) float f32x4;
typedef __attribute__((ext_vector_type(16))) float f32x16;
typedef __attribute__((ext_vector_type(8))) int i32x8;

#define KP 352
#define MROWS 131072

__device__ __forceinline__ ushort_t f2bf(float f) {
  union { float f; uint32_t u; } v; v.f = f;
  uint32_t r = v.u + 0x7FFFu + ((v.u >> 16) & 1u);   // RNE
  return (ushort_t)(r >> 16);
}
__device__ __forceinline__ float bf2f(ushort_t u) {
  union { uint32_t u; float f; } v; v.u = ((uint32_t)u) << 16;
  return v.f;
}

__device__ __forceinline__ void gl_lds16(const void* g, void* l) {
  __builtin_amdgcn_global_load_lds(
      (const __attribute__((address_space(1))) void*)g,
      (__attribute__((address_space(3))) void*)l, 16, 0, 0);
}

// ---------------- prep kernels ----------------

__global__ void k_cast_f8(const float* __restrict__ src, uint32_t* __restrict__ dst,
                          int n4, float scale) {
  for (int i = blockIdx.x * 256 + threadIdx.x; i < n4; i += gridDim.x * 256) {
    float4 v = ((const float4*)src)[i];
    int r = __builtin_amdgcn_cvt_pk_fp8_f32(v.x * scale, v.y * scale, 0, 0);
    r = __builtin_amdgcn_cvt_pk_fp8_f32(v.z * scale, v.w * scale, r, 1);
    dst[i] = (uint32_t)r;
  }
}

__global__ void k_build_X(const float* __restrict__ inputs, const float* __restrict__ hx,
                          ushort_t* __restrict__ Xbf, uint8_t* __restrict__ Xf8) {
  int r = blockIdx.x;
  int b = r / 66, c = r - b * 66;
  const float* src = (c < 2) ? (inputs + ((size_t)b * 2 + c) * 2048)
                             : (hx + ((size_t)b * 64 + (c - 2)) * 2048);
  ushort_t* d1 = Xbf + (size_t)r * 2048;
  uint8_t* d2 = Xf8 + (size_t)r * 2048;
  for (int n = threadIdx.x * 4; n < 2048; n += 256 * 4) {
    float4 v = *(const float4*)(src + n);
    ushort4 rr;
    rr.x = f2bf(v.x); rr.y = f2bf(v.y); rr.z = f2bf(v.z); rr.w = f2bf(v.w);
    *(ushort4*)(d1 + n) = rr;
    int r8 = __builtin_amdgcn_cvt_pk_fp8_f32(v.x, v.y, 0, 0);
    r8 = __builtin_amdgcn_cvt_pk_fp8_f32(v.z, v.w, r8, 1);
    *(uint32_t*)(d2 + n) = (uint32_t)r8;
  }
}

__global__ void k_pack_W(const float* __restrict__ Wru, const float* __restrict__ Wc,
                         ushort_t* __restrict__ Wtru, ushort_t* __restrict__ Wtc) {
  int o = blockIdx.x;
  const float* W = (o < 128) ? Wru : Wc;
  int O = (o < 128) ? 128 : 64;
  int oo = (o < 128) ? o : (o - 128);
  ushort_t* Wt = (o < 128) ? Wtru : Wtc;
  for (int k = threadIdx.x; k < KP; k += 256) {
    float v = (k < 330 && oo < O) ? W[(size_t)k * O + oo] : 0.f;
    Wt[(size_t)oo * KP + k] = f2bf(v);
  }
}

// Ht[(b*2048+n)][0..66) = Xbf[(b*66+c)][n]. grid (16, 64) — conv1 only
__global__ __launch_bounds__(256) void k_trans_slot0(const ushort_t* __restrict__ Xbf,
                                                     ushort_t* __restrict__ Ht) {
  __shared__ ushort_t t[66 * 136];
  const int tid = threadIdx.x;
  const int b = blockIdx.y;
  const int n0 = blockIdx.x * 128;
  for (int idx = tid; idx < 66 * 16; idx += 256) {
    int c = idx >> 4, seg = idx & 15;
    bf16x8 v = *(const bf16x8*)&Xbf[((size_t)b * 66 + c) * 2048 + n0 + seg * 8];
    *(bf16x8*)&t[c * 136 + seg * 8] = v;
  }
  __syncthreads();
  for (int idx = tid; idx < 128 * 33; idx += 256) {
    int nn = idx / 33, pc = idx - nn * 33;
    int c = pc * 2;
    uint32_t pk = (uint32_t)t[c * 136 + nn] | ((uint32_t)t[(c + 1) * 136 + nn] << 16);
    *(uint32_t*)&Ht[((size_t)b * 2048 + n0 + nn) * KP + c] = pk;
  }
}

// ---------------- MX-fp8 diffusion GEMM (BK=64, counted-vmcnt dbuf) ----------------
// r12-validated (86us/dispatch). C[r,m] = sum_k A[r,k]*B[m,k], 32 tiles BK=64.
// Loop: STAGE(next -> other buf); vmcnt(4); s_barrier; sched_barrier;
//       COMPUTE(cur); s_barrier(raw). Next tile's loads in flight across both
// barriers. LDS 33280 (dbuf 2x16KB + cTile union) -> 4 blocks/CU.
// MODE 0: A=Xf8 (scale 1), writes Ht slot (1+2g) bf16 + Y1f8 = fp8(32*v).
// MODE 1: A=Y1f8+g*2048 (scale 2^-5), Ht slot (2+2g) = bf16(2v - Xres).
// B always Abf8 (scale 2^-9).
template <int MODE>
__global__ __launch_bounds__(256, 4) void gemm_bt(
    const uint8_t* __restrict__ Aop, int lda,
    const uint8_t* __restrict__ Bop,
    const ushort_t* __restrict__ Xres,
    uint8_t* __restrict__ Y1f8,
    ushort_t* __restrict__ Ht) {
  __shared__ char smem[33280];   // dbuf 2x16KB; epilogue cTile 128x130 ushort
  ushort_t* smemU = (ushort_t*)smem;
  const int tid = threadIdx.x;
  const int l = tid & 63, w = tid >> 6;
  const int wr = w >> 1, wc = w & 1;
  const int rowL = l & 31;
  const int kh = l >> 5;
  const int m7 = (rowL >> 2) & 7;

  // XCD-aware bijective remap (1056 = 8 * 132; 132 = 4 nb * 33 mb)
  const int fid = blockIdx.y * 33 + blockIdx.x;
  const int xcd = fid & 7;
  const int idx = fid >> 3;
  const int nb = xcd * 4 + idx / 33;
  const int mb = idx % 33;
  const int r0 = mb * 128;
  const int m0 = nb * 128;
  const int g = m0 >> 11;
  if (MODE == 1) Aop += (size_t)g * 2048;

  const int SA = (MODE == 0) ? 0x7F7F7F7F : 0x7A7A7A7A;  // 1.0 / 2^-5
  const int SB = 0x76767676;                             // 2^-9

  f32x16 acc[2][2];
#pragma unroll
  for (int mi = 0; mi < 2; ++mi)
#pragma unroll
    for (int ni = 0; ni < 2; ++ni)
#pragma unroll
      for (int q = 0; q < 16; ++q) acc[mi][ni][q] = 0.f;

  const int d = tid;
  const int srow = ((d >> 3) << 2) | (((d >> 1) ^ (d >> 4)) & 1) |
                   ((((d >> 2) ^ (d >> 5)) & 1) << 1);
  const int sj = (d ^ (d >> 3)) & 1;
  const uint8_t* pA = Aop + (size_t)(r0 + srow) * lda + sj * 16;
  const uint8_t* pB = Bop + (size_t)(m0 + srow) * 2048 + sj * 16;

  const int sj0 = ((rowL * 2) ^ m7) * 16;
  const int sj1 = ((rowL * 2 + 1) ^ m7) * 16;
  const int aw = wr * 2048;   // A-side wave offset within 4KB region (64 rows)
  const int bw = wc * 2048;   // B-side wave offset

#define STAGEF(TT, BB)                                                       \
  {                                                                          \
    const int kb_ = (TT) * 64;                                               \
    gl_lds16(pA + kb_,      smem + (BB) + tid * 16);                         \
    gl_lds16(pA + kb_ + 32, smem + (BB) + 4096 + tid * 16);                  \
    gl_lds16(pB + kb_,      smem + (BB) + 8192 + tid * 16);                  \
    gl_lds16(pB + kb_ + 32, smem + (BB) + 8192 + 4096 + tid * 16);           \
  }

#define COMPUTEF(BB)                                                         \
  {                                                                          \
    const int rbase = kh * 4096;                                             \
    union { uint4 q[2]; i32x8 v; } bu[2], au;                                \
    _Pragma("unroll")                                                        \
    for (int ni = 0; ni < 2; ++ni) {                                         \
      const char* bp = smem + (BB) + 8192 + rbase + bw + ni * 1024;          \
      bu[ni].q[0] = *(const uint4*)(bp + sj0);                               \
      bu[ni].q[1] = *(const uint4*)(bp + sj1);                               \
    }                                                                        \
    _Pragma("unroll")                                                        \
    for (int mi = 0; mi < 2; ++mi) {                                         \
      const char* ap = smem + (BB) + rbase + aw + mi * 1024;                 \
      au.q[0] = *(const uint4*)(ap + sj0);                                   \
      au.q[1] = *(const uint4*)(ap + sj1);                                   \
      _Pragma("unroll")                                                      \
      for (int ni = 0; ni < 2; ++ni)                                         \
        acc[mi][ni] = __builtin_amdgcn_mfma_scale_f32_32x32x64_f8f6f4(       \
            au.v, bu[ni].v, acc[mi][ni], 0, 0, 0, SA, 0, SB);                \
    }                                                                        \
  }

  // K-stagger: co-resident blocks start at different K tiles
  const int kt0 = (idx & 3) * 8;
  STAGEF(kt0, 0);
#pragma unroll 1
  for (int ktt = 0; ktt < 32; ++ktt) {
    const int cur = (ktt & 1) * 16384;
    if (ktt + 1 < 32) {
      STAGEF(((ktt + 1 + kt0) & 31), cur ^ 16384);
      asm volatile("s_waitcnt vmcnt(4)" ::: "memory");
    } else {
      asm volatile("s_waitcnt vmcnt(0)" ::: "memory");
    }
    __builtin_amdgcn_s_barrier();
    __builtin_amdgcn_sched_barrier(0);
    COMPUTEF(cur);
    __builtin_amdgcn_s_barrier();   // raw: protect next overwrite (no drain)
  }

#undef STAGEF
#undef COMPUTEF

  // ---------------- epilogue (r10/r12 validated) ----------------
  // C layout (32x32): col = lane&31, row = (q&3) + 8*(q>>2) + 4*(lane>>5)
#pragma unroll
  for (int mi = 0; mi < 2; ++mi) {
#pragma unroll
    for (int ni = 0; ni < 2; ++ni) {
      const int clb = wc * 64 + ni * 32 + rowL;
#pragma unroll
      for (int q = 0; q < 16; ++q) {
        const int rl = wr * 64 + mi * 32 + (q & 3) + 8 * (q >> 2) + 4 * kh;
        float v = acc[mi][ni][q];
        if (MODE == 1)
          v = 2.f * v - bf2f(Xres[(size_t)(r0 + rl) * 2048 + ((m0 + clb) & 2047)]);
        smemU[clb * 130 + rl] = f2bf(v);
      }
    }
  }
  __syncthreads();

  // dword-packed transposed write into Ht (pairs (rl, rl+1) same b, even c)
  const int slotBase = (MODE == 0 ? 1 : 2) + 2 * g;
  const int n_base = m0 & 2047;
#pragma unroll 4
  for (int j2 = 0; j2 < 32; ++j2) {
    int idx2 = j2 * 256 + tid;
    int mc = idx2 >> 6, pr = idx2 & 63;
    int rl = pr * 2;
    unsigned rg = (unsigned)(r0 + rl);
    unsigned b = rg / 66u;
    unsigned c = rg - b * 66u;          // even
    int n = n_base + mc;
    uint32_t pk = (uint32_t)smemU[mc * 130 + rl] |
                  ((uint32_t)smemU[mc * 130 + rl + 1] << 16);
    *(uint32_t*)&Ht[((size_t)b * 2048 + n) * KP + slotBase * 66 + c] = pk;
  }

  // Y1f8 pass (MODE 0): fp8(32*v), dword-packed, coalesced
  if (MODE == 0) {
#pragma unroll 4
    for (int it = 0; it < 16; ++it) {
      int idx2 = it * 256 + tid;
      int rl = idx2 >> 5, mq = idx2 & 31;
      float v0 = bf2f(smemU[(mq * 4 + 0) * 130 + rl]) * 32.f;
      float v1 = bf2f(smemU[(mq * 4 + 1) * 130 + rl]) * 32.f;
      float v2 = bf2f(smemU[(mq * 4 + 2) * 130 + rl]) * 32.f;
      float v3 = bf2f(smemU[(mq * 4 + 3) * 130 + rl]) * 32.f;
      int r8 = __builtin_amdgcn_cvt_pk_fp8_f32(v0, v1, 0, 0);
      r8 = __builtin_amdgcn_cvt_pk_fp8_f32(v2, v3, r8, 1);
      *(uint32_t*)(Y1f8 + (size_t)(r0 + rl) * 4096 + m0 + mq * 4) = (uint32_t)r8;
    }
  }
}

// ---------------- MFMA projection GEMM (counted-vmcnt K-loop) ----------------
// MODE 0 (RU): s=sigmoid; Xbf/Xf8 rows 2..65 = r*hx, Ubuf = u, Ht slot0
//              cols 2..65 = bf16(r*hx) transposed.
// MODE 1 (CF): out = u*hx + (1-u)*tanh(...).
template <int MODE>
__global__ __launch_bounds__(256, 4) void proj_mfma(
    const ushort_t* __restrict__ Ht_c, const ushort_t* __restrict__ Wt,
    const float* __restrict__ bias, const float* __restrict__ hx,
    ushort_t* __restrict__ Xbf, uint8_t* __restrict__ Xf8,
    ushort_t* __restrict__ Ubuf, ushort_t* __restrict__ HtW,
    float* __restrict__ out) {
  __shared__ ushort_t smem[16640];
  const int tid = threadIdx.x;
  const int l = tid & 63, w = tid >> 6;
  const int wr = w >> 1, wc = w & 1;
  const int lr = l & 15, lk = l >> 4;
  const int bb = blockIdx.x >> 4;
  const int n0 = (blockIdx.x & 15) * 128;
  const size_t m0 = (size_t)bb * 2048 + n0;

  f32x4 acc[4][4];
  const f32x4 zero = {0.f, 0.f, 0.f, 0.f};
#pragma unroll
  for (int mi = 0; mi < 4; mi++)
#pragma unroll
    for (int ni = 0; ni < 4; ni++) acc[mi][ni] = zero;

  const int srow = tid >> 2;
  const int kcol = ((tid & 3) ^ ((tid >> 3) & 3)) * 8;
  const ushort_t* pA = Ht_c + (m0 + srow) * KP + kcol;
  const ushort_t* pB = Wt + (size_t)srow * KP + kcol;
  const int so = (lk ^ ((lr >> 1) & 3)) * 8;

#define STAGEP(KT, BB)                                                         \
  {                                                                            \
    const int kp_ = (KT) * 32;                                                 \
    gl_lds16(pA + kp_, (void*)&smem[(BB) + tid * 8]);                          \
    gl_lds16(pA + (size_t)64 * KP + kp_, (void*)&smem[(BB) + 2048 + tid * 8]); \
    gl_lds16(pB + kp_, (void*)&smem[(BB) + 4096 + tid * 8]);                   \
    gl_lds16(pB + (size_t)64 * KP + kp_, (void*)&smem[(BB) + 6144 + tid * 8]); \
  }

#define COMPUTEP(BB)                                                           \
  {                                                                            \
    bf16x8 af[4], bfv[4];                                                      \
    _Pragma("unroll")                                                          \
    for (int i = 0; i < 4; i++)                                                \
      af[i] = *(const bf16x8*)&smem[(BB) + (wr * 64 + i * 16 + lr) * 32 + so]; \
    _Pragma("unroll")                                                          \
    for (int i = 0; i < 4; i++)                                                \
      bfv[i] = *(const bf16x8*)&smem[(BB) + 4096 + (wc * 64 + i * 16 + lr) * 32 + so]; \
    _Pragma("unroll")                                                          \
    for (int mi = 0; mi < 4; mi++)                                             \
      _Pragma("unroll")                                                        \
      for (int ni = 0; ni < 4; ni++)                                           \
        acc[mi][ni] = __builtin_amdgcn_mfma_f32_16x16x32_bf16(af[mi], bfv[ni], \
                                                              acc[mi][ni], 0, 0, 0); \
  }

  STAGEP(0, 0);
#pragma unroll 1
  for (int kt = 0; kt < 11; ++kt) {
    if (kt + 1 < 11) {
      STAGEP(kt + 1, ((kt + 1) & 1) * 8192);
      asm volatile("s_waitcnt vmcnt(4)" ::: "memory");
    } else {
      asm volatile("s_waitcnt vmcnt(0)" ::: "memory");
    }
    __builtin_amdgcn_s_barrier();
    __builtin_amdgcn_sched_barrier(0);
    COMPUTEP((kt & 1) * 8192);
    __builtin_amdgcn_s_barrier();
  }

#undef STAGEP
#undef COMPUTEP

  // activation into transposed LDS tile sTile[o][m]
#pragma unroll
  for (int mi = 0; mi < 4; mi++) {
#pragma unroll
    for (int ni = 0; ni < 4; ni++) {
      const int rl0 = wr * 64 + mi * 16 + lk * 4;
      const int o = wc * 64 + ni * 16 + lr;
      float bv = (MODE == 0 || o < 64) ? bias[o] : 0.f;
#pragma unroll
      for (int j = 0; j < 4; j++) {
        float v = acc[mi][ni][j] + bv;
        float s;
        if (MODE == 0) s = 1.f / (1.f + expf(-v));
        else           s = tanhf(v);
        smem[o * 130 + rl0 + j] = f2bf(s);
      }
    }
  }
  __syncthreads();

  if (MODE == 0) {
    // pass 1: o<64 -> smem = r*hx (hx read coalesced); o>=64 -> Ubuf = u
#pragma unroll 4
    for (int j2 = 0; j2 < 64; ++j2) {
      int idx = j2 * 256 + tid;
      int o = idx >> 7, m = idx & 127;
      ushort_t sv = smem[o * 130 + m];
      if (o < 64) {
        float p = bf2f(sv) * hx[((size_t)bb * 64 + o) * 2048 + n0 + m];
        smem[o * 130 + m] = f2bf(p);
      } else {
        Ubuf[((size_t)bb * 64 + (o - 64)) * 2048 + n0 + m] = sv;
      }
    }
    __syncthreads();
    // pass 2: Xbf (ushort4) + Xf8 (dword) rows, coalesced
#pragma unroll 2
    for (int j2 = 0; j2 < 8; ++j2) {
      int idx = j2 * 256 + tid;
      int o = idx >> 5, m4 = (idx & 31) * 4;
      ushort_t s0 = smem[o * 130 + m4 + 0], s1 = smem[o * 130 + m4 + 1];
      ushort_t s2 = smem[o * 130 + m4 + 2], s3 = smem[o * 130 + m4 + 3];
      ushort4 pk4; pk4.x = s0; pk4.y = s1; pk4.z = s2; pk4.w = s3;
      *(ushort4*)&Xbf[((size_t)bb * 66 + 2 + o) * 2048 + n0 + m4] = pk4;
      int r8 = __builtin_amdgcn_cvt_pk_fp8_f32(bf2f(s0), bf2f(s1), 0, 0);
      r8 = __builtin_amdgcn_cvt_pk_fp8_f32(bf2f(s2), bf2f(s3), r8, 1);
      *(uint32_t*)(Xf8 + ((size_t)bb * 66 + 2 + o) * 2048 + n0 + m4) = (uint32_t)r8;
    }
    // pass 3: Ht slot0 cols 2..65 transposed, dword-packed (o even pairs)
#pragma unroll 2
    for (int j2 = 0; j2 < 16; ++j2) {
      int idx = j2 * 256 + tid;
      int m = idx >> 5, po = idx & 31;
      int o = po * 2;
      uint32_t pk = (uint32_t)smem[o * 130 + m] |
                    ((uint32_t)smem[(o + 1) * 130 + m] << 16);
      *(uint32_t*)&HtW[((size_t)bb * 2048 + n0 + m) * KP + 2 + o] = pk;
    }
  } else {
#pragma unroll 4
    for (int j2 = 0; j2 < 32; ++j2) {
      int idx = j2 * 256 + tid;
      int o = idx >> 7, m = idx & 127;
      float Cv = bf2f(smem[o * 130 + m]);
      int n = n0 + m;
      size_t oi = ((size_t)bb * 64 + o) * 2048 + n;
      float u = bf2f(Ubuf[oi]);
      out[oi] = u * hx[oi] + (1.f - u) * Cv;
    }
  }
}

// ---------------- launcher ----------------

extern "C" void kernel_launch(void* const* d_in, const int* in_sizes, int n_in,
                              void* d_out, int out_size, void* d_ws, size_t ws_size,
                              hipStream_t stream) {
  (void)in_sizes; (void)n_in; (void)out_size; (void)ws_size;
  const float* inputs = (const float*)d_in[0];
  const float* hx     = (const float*)d_in[1];
  const float* s0     = (const float*)d_in[2];
  const float* s1     = (const float*)d_in[3];
  const float* W_ru   = (const float*)d_in[4];
  const float* b_ru   = (const float*)d_in[5];
  const float* W_c    = (const float*)d_in[6];
  const float* b_c    = (const float*)d_in[7];
  float* out = (float*)d_out;

  char* p = (char*)d_ws;
  uint8_t*  Abf8 = (uint8_t*)p;  p += (size_t)4096 * 2048;        //  8.39 MB
  ushort_t* Xbf  = (ushort_t*)p; p += (size_t)4224 * 2048 * 2;    // 17.30 MB
  uint8_t*  Xf8  = (uint8_t*)p;  p += (size_t)4224 * 2048;        //  8.65 MB
  uint8_t*  Y1f8 = (uint8_t*)p;  p += (size_t)4224 * 4096;        // 17.30 MB
  ushort_t* Ht   = (ushort_t*)p; p += (size_t)MROWS * KP * 2;     // 92.27 MB
  ushort_t* Ubuf = (ushort_t*)p; p += (size_t)64 * 64 * 2048 * 2; // 16.78 MB
  ushort_t* Wtru = (ushort_t*)p; p += (size_t)128 * KP * 2;       // 90 KB
  ushort_t* Wtc  = (ushort_t*)p; p += (size_t)128 * KP * 2;       // 90 KB

  k_cast_f8<<<1024, 256, 0, stream>>>(s0, (uint32_t*)Abf8, 1048576, 512.f);
  k_cast_f8<<<1024, 256, 0, stream>>>(s1, (uint32_t*)(Abf8 + 4194304), 1048576, 512.f);
  k_build_X<<<4224, 256, 0, stream>>>(inputs, hx, Xbf, Xf8);
  k_pack_W<<<192, 256, 0, stream>>>(W_ru, W_c, Wtru, Wtc);

  dim3 g(33, 32);
  dim3 gt(16, 64);
  // conv 1
  k_trans_slot0<<<gt, 256, 0, stream>>>(Xbf, Ht);
  gemm_bt<0><<<g, 256, 0, stream>>>(Xf8, 2048, Abf8, nullptr, Y1f8, Ht);
  gemm_bt<1><<<g, 256, 0, stream>>>(Y1f8, 4096, Abf8, Xbf, nullptr, Ht);
  proj_mfma<0><<<1024, 256, 0, stream>>>(Ht, Wtru, b_ru, hx, Xbf, Xf8, Ubuf, Ht, nullptr);
  // conv 2 (slot0 cols 0,1 persist; cols 2..65 written by proj_mfma<0>)
  gemm_bt<0><<<g, 256, 0, stream>>>(Xf8, 2048, Abf8, nullptr, Y1f8, Ht);
  gemm_bt<1><<<g, 256, 0, stream>>>(Y1f8, 4096, Abf8, Xbf, nullptr, Ht);
  proj_mfma<1><<<1024, 256, 0, stream>>>(Ht, Wtc, b_c, hx, nullptr, nullptr, Ubuf, nullptr, out);
}

// Round 15
// 409.576 us; speedup vs baseline: 1.6571x; 1.0053x over previous
//
#include <hip/hip_runtime.h>
#include <stdint.h>

// DCGRU cell on MI355X — round 15: r14 (best, 412us) + all prep fused into one
// dispatch (cast x2, build_X, pack_W, trans_slot0 are mutually independent).
//
// Buffers (d_ws, ~161 MB):
//   Abf8 [4096][2048] u8    supports stacked [A0;A1] x512 (e4m3)
//   Xbf  [4224][2048] bf16  X rows (b*66+c); rows 2..65 overwritten r*hx
//   Xf8  [4224][2048] u8    X in e4m3 (same row layout)
//   Y1f8 [4224][4096] u8    x1 (both supports) x32 (e4m3)
//   Ht   [131072][352] bf16 packed H^T: row m=(b*2048+n), col K = slot*66+c
//   Ubuf [64*64*2048] bf16  u gate
//   Wt_ru/Wt_c [128][352] bf16

typedef unsigned short ushort_t;
typedef __attribute__((ext_vector_type(8))) __bf16 bf16x8;
typedef __attribute__((ext_vector_type(4))) float f32x4;
typedef __attribute__((ext_vector_type(16))) float f32x16;
typedef __attribute__((ext_vector_type(8))) int i32x8;

#define KP 352
#define MROWS 131072

__device__ __forceinline__ ushort_t f2bf(float f) {
  union { float f; uint32_t u; } v; v.f = f;
  uint32_t r = v.u + 0x7FFFu + ((v.u >> 16) & 1u);   // RNE
  return (ushort_t)(r >> 16);
}
__device__ __forceinline__ float bf2f(ushort_t u) {
  union { uint32_t u; float f; } v; v.u = ((uint32_t)u) << 16;
  return v.f;
}

__device__ __forceinline__ void gl_lds16(const void* g, void* l) {
  __builtin_amdgcn_global_load_lds(
      (const __attribute__((address_space(1))) void*)g,
      (__attribute__((address_space(3))) void*)l, 16, 0, 0);
}

// ---------------- fused prep kernel ----------------
// blocks [0,1024): cast s0/s1 -> Abf8 (x512 e4m3), 512 blocks each, grid-stride
// blocks [1024,5248): build_X row r = blk-1024 -> Xbf (bf16) + Xf8 (e4m3)
// blocks [5248,5440): pack W column o = blk-5248 -> Wtru / Wtc
// blocks [5440,6464): trans slot0: t = blk-5440, bx=t&15, by=t>>4 -> Ht cols 0..65
__global__ __launch_bounds__(256) void k_prep(
    const float* __restrict__ inputs, const float* __restrict__ hx,
    const float* __restrict__ s0, const float* __restrict__ s1,
    const float* __restrict__ Wru, const float* __restrict__ Wc,
    uint8_t* __restrict__ Abf8, ushort_t* __restrict__ Xbf,
    uint8_t* __restrict__ Xf8, ushort_t* __restrict__ Wtru,
    ushort_t* __restrict__ Wtc, ushort_t* __restrict__ Ht) {
  __shared__ ushort_t t[66 * 136];
  const int blk = blockIdx.x;
  const int tid = threadIdx.x;

  if (blk < 1024) {
    // support casts (x512): blk<512 -> s0, else s1
    const float* src = (blk < 512) ? s0 : s1;
    uint32_t* dst = (uint32_t*)(Abf8 + (size_t)(blk < 512 ? 0 : 4194304));
    const int bid = blk & 511;
    for (int i = bid * 256 + tid; i < 1048576; i += 512 * 256) {
      float4 v = ((const float4*)src)[i];
      int r = __builtin_amdgcn_cvt_pk_fp8_f32(v.x * 512.f, v.y * 512.f, 0, 0);
      r = __builtin_amdgcn_cvt_pk_fp8_f32(v.z * 512.f, v.w * 512.f, r, 1);
      dst[i] = (uint32_t)r;
    }
  } else if (blk < 5248) {
    // build X row
    int r = blk - 1024;
    int b = r / 66, c = r - b * 66;
    const float* src = (c < 2) ? (inputs + ((size_t)b * 2 + c) * 2048)
                               : (hx + ((size_t)b * 64 + (c - 2)) * 2048);
    ushort_t* d1 = Xbf + (size_t)r * 2048;
    uint8_t* d2 = Xf8 + (size_t)r * 2048;
    for (int n = tid * 4; n < 2048; n += 256 * 4) {
      float4 v = *(const float4*)(src + n);
      ushort4 rr;
      rr.x = f2bf(v.x); rr.y = f2bf(v.y); rr.z = f2bf(v.z); rr.w = f2bf(v.w);
      *(ushort4*)(d1 + n) = rr;
      int r8 = __builtin_amdgcn_cvt_pk_fp8_f32(v.x, v.y, 0, 0);
      r8 = __builtin_amdgcn_cvt_pk_fp8_f32(v.z, v.w, r8, 1);
      *(uint32_t*)(d2 + n) = (uint32_t)r8;
    }
  } else if (blk < 5440) {
    // pack W
    int o = blk - 5248;
    const float* W = (o < 128) ? Wru : Wc;
    int O = (o < 128) ? 128 : 64;
    int oo = (o < 128) ? o : (o - 128);
    ushort_t* Wt = (o < 128) ? Wtru : Wtc;
    for (int k = tid; k < KP; k += 256) {
      float v = (k < 330 && oo < O) ? W[(size_t)k * O + oo] : 0.f;
      Wt[(size_t)oo * KP + k] = f2bf(v);
    }
  } else {
    // trans slot0 (r11-validated f32-source variant; bit-identical to Xbf path)
    int tt = blk - 5440;
    const int b = tt >> 4;
    const int n0 = (tt & 15) * 128;
    for (int idx = tid; idx < 66 * 16; idx += 256) {
      int c = idx >> 4, seg = idx & 15;
      const float* src = (c < 2) ? (inputs + ((size_t)b * 2 + c) * 2048)
                                 : (hx + ((size_t)b * 64 + (c - 2)) * 2048);
      float4 v0 = *(const float4*)(src + n0 + seg * 8);
      float4 v1 = *(const float4*)(src + n0 + seg * 8 + 4);
      ushort_t* dp = &t[c * 136 + seg * 8];
      dp[0] = f2bf(v0.x); dp[1] = f2bf(v0.y); dp[2] = f2bf(v0.z); dp[3] = f2bf(v0.w);
      dp[4] = f2bf(v1.x); dp[5] = f2bf(v1.y); dp[6] = f2bf(v1.z); dp[7] = f2bf(v1.w);
    }
    __syncthreads();
    for (int idx = tid; idx < 128 * 33; idx += 256) {
      int nn = idx / 33, pc = idx - nn * 33;
      int c = pc * 2;
      uint32_t pk = (uint32_t)t[c * 136 + nn] | ((uint32_t)t[(c + 1) * 136 + nn] << 16);
      *(uint32_t*)&Ht[((size_t)b * 2048 + n0 + nn) * KP + c] = pk;
    }
  }
}

// ---------------- MX-fp8 diffusion GEMM (BK=64, counted-vmcnt dbuf) ----------------
// r12-validated (86us/dispatch). C[r,m] = sum_k A[r,k]*B[m,k], 32 tiles BK=64.
// Loop: STAGE(next -> other buf); vmcnt(4); s_barrier; sched_barrier;
//       COMPUTE(cur); s_barrier(raw). Next tile's loads in flight across both
// barriers. LDS 33280 (dbuf 2x16KB + cTile union) -> 4 blocks/CU.
// MODE 0: A=Xf8 (scale 1), writes Ht slot (1+2g) bf16 + Y1f8 = fp8(32*v).
// MODE 1: A=Y1f8+g*2048 (scale 2^-5), Ht slot (2+2g) = bf16(2v - Xres).
// B always Abf8 (scale 2^-9).
template <int MODE>
__global__ __launch_bounds__(256, 4) void gemm_bt(
    const uint8_t* __restrict__ Aop, int lda,
    const uint8_t* __restrict__ Bop,
    const ushort_t* __restrict__ Xres,
    uint8_t* __restrict__ Y1f8,
    ushort_t* __restrict__ Ht) {
  __shared__ char smem[33280];   // dbuf 2x16KB; epilogue cTile 128x130 ushort
  ushort_t* smemU = (ushort_t*)smem;
  const int tid = threadIdx.x;
  const int l = tid & 63, w = tid >> 6;
  const int wr = w >> 1, wc = w & 1;
  const int rowL = l & 31;
  const int kh = l >> 5;
  const int m7 = (rowL >> 2) & 7;

  // XCD-aware bijective remap (1056 = 8 * 132; 132 = 4 nb * 33 mb)
  const int fid = blockIdx.y * 33 + blockIdx.x;
  const int xcd = fid & 7;
  const int idx = fid >> 3;
  const int nb = xcd * 4 + idx / 33;
  const int mb = idx % 33;
  const int r0 = mb * 128;
  const int m0 = nb * 128;
  const int g = m0 >> 11;
  if (MODE == 1) Aop += (size_t)g * 2048;

  const int SA = (MODE == 0) ? 0x7F7F7F7F : 0x7A7A7A7A;  // 1.0 / 2^-5
  const int SB = 0x76767676;                             // 2^-9

  f32x16 acc[2][2];
#pragma unroll
  for (int mi = 0; mi < 2; ++mi)
#pragma unroll
    for (int ni = 0; ni < 2; ++ni)
#pragma unroll
      for (int q = 0; q < 16; ++q) acc[mi][ni][q] = 0.f;

  const int d = tid;
  const int srow = ((d >> 3) << 2) | (((d >> 1) ^ (d >> 4)) & 1) |
                   ((((d >> 2) ^ (d >> 5)) & 1) << 1);
  const int sj = (d ^ (d >> 3)) & 1;
  const uint8_t* pA = Aop + (size_t)(r0 + srow) * lda + sj * 16;
  const uint8_t* pB = Bop + (size_t)(m0 + srow) * 2048 + sj * 16;

  const int sj0 = ((rowL * 2) ^ m7) * 16;
  const int sj1 = ((rowL * 2 + 1) ^ m7) * 16;
  const int aw = wr * 2048;   // A-side wave offset within 4KB region (64 rows)
  const int bw = wc * 2048;   // B-side wave offset

#define STAGEF(TT, BB)                                                       \
  {                                                                          \
    const int kb_ = (TT) * 64;                                               \
    gl_lds16(pA + kb_,      smem + (BB) + tid * 16);                         \
    gl_lds16(pA + kb_ + 32, smem + (BB) + 4096 + tid * 16);                  \
    gl_lds16(pB + kb_,      smem + (BB) + 8192 + tid * 16);                  \
    gl_lds16(pB + kb_ + 32, smem + (BB) + 8192 + 4096 + tid * 16);           \
  }

#define COMPUTEF(BB)                                                         \
  {                                                                          \
    const int rbase = kh * 4096;                                             \
    union { uint4 q[2]; i32x8 v; } bu[2], au;                                \
    _Pragma("unroll")                                                        \
    for (int ni = 0; ni < 2; ++ni) {                                         \
      const char* bp = smem + (BB) + 8192 + rbase + bw + ni * 1024;          \
      bu[ni].q[0] = *(const uint4*)(bp + sj0);                               \
      bu[ni].q[1] = *(const uint4*)(bp + sj1);                               \
    }                                                                        \
    _Pragma("unroll")                                                        \
    for (int mi = 0; mi < 2; ++mi) {                                         \
      const char* ap = smem + (BB) + rbase + aw + mi * 1024;                 \
      au.q[0] = *(const uint4*)(ap + sj0);                                   \
      au.q[1] = *(const uint4*)(ap + sj1);                                   \
      _Pragma("unroll")                                                      \
      for (int ni = 0; ni < 2; ++ni)                                         \
        acc[mi][ni] = __builtin_amdgcn_mfma_scale_f32_32x32x64_f8f6f4(       \
            au.v, bu[ni].v, acc[mi][ni], 0, 0, 0, SA, 0, SB);                \
    }                                                                        \
  }

  // K-stagger: co-resident blocks start at different K tiles
  const int kt0 = (idx & 3) * 8;
  STAGEF(kt0, 0);
#pragma unroll 1
  for (int ktt = 0; ktt < 32; ++ktt) {
    const int cur = (ktt & 1) * 16384;
    if (ktt + 1 < 32) {
      STAGEF(((ktt + 1 + kt0) & 31), cur ^ 16384);
      asm volatile("s_waitcnt vmcnt(4)" ::: "memory");
    } else {
      asm volatile("s_waitcnt vmcnt(0)" ::: "memory");
    }
    __builtin_amdgcn_s_barrier();
    __builtin_amdgcn_sched_barrier(0);
    COMPUTEF(cur);
    __builtin_amdgcn_s_barrier();   // raw: protect next overwrite (no drain)
  }

#undef STAGEF
#undef COMPUTEF

  // ---------------- epilogue (r10/r12 validated) ----------------
  // C layout (32x32): col = lane&31, row = (q&3) + 8*(q>>2) + 4*(lane>>5)
#pragma unroll
  for (int mi = 0; mi < 2; ++mi) {
#pragma unroll
    for (int ni = 0; ni < 2; ++ni) {
      const int clb = wc * 64 + ni * 32 + rowL;
#pragma unroll
      for (int q = 0; q < 16; ++q) {
        const int rl = wr * 64 + mi * 32 + (q & 3) + 8 * (q >> 2) + 4 * kh;
        float v = acc[mi][ni][q];
        if (MODE == 1)
          v = 2.f * v - bf2f(Xres[(size_t)(r0 + rl) * 2048 + ((m0 + clb) & 2047)]);
        smemU[clb * 130 + rl] = f2bf(v);
      }
    }
  }
  __syncthreads();

  // dword-packed transposed write into Ht (pairs (rl, rl+1) same b, even c)
  const int slotBase = (MODE == 0 ? 1 : 2) + 2 * g;
  const int n_base = m0 & 2047;
#pragma unroll 4
  for (int j2 = 0; j2 < 32; ++j2) {
    int idx2 = j2 * 256 + tid;
    int mc = idx2 >> 6, pr = idx2 & 63;
    int rl = pr * 2;
    unsigned rg = (unsigned)(r0 + rl);
    unsigned b = rg / 66u;
    unsigned c = rg - b * 66u;          // even
    int n = n_base + mc;
    uint32_t pk = (uint32_t)smemU[mc * 130 + rl] |
                  ((uint32_t)smemU[mc * 130 + rl + 1] << 16);
    *(uint32_t*)&Ht[((size_t)b * 2048 + n) * KP + slotBase * 66 + c] = pk;
  }

  // Y1f8 pass (MODE 0): fp8(32*v), dword-packed, coalesced
  if (MODE == 0) {
#pragma unroll 4
    for (int it = 0; it < 16; ++it) {
      int idx2 = it * 256 + tid;
      int rl = idx2 >> 5, mq = idx2 & 31;
      float v0 = bf2f(smemU[(mq * 4 + 0) * 130 + rl]) * 32.f;
      float v1 = bf2f(smemU[(mq * 4 + 1) * 130 + rl]) * 32.f;
      float v2 = bf2f(smemU[(mq * 4 + 2) * 130 + rl]) * 32.f;
      float v3 = bf2f(smemU[(mq * 4 + 3) * 130 + rl]) * 32.f;
      int r8 = __builtin_amdgcn_cvt_pk_fp8_f32(v0, v1, 0, 0);
      r8 = __builtin_amdgcn_cvt_pk_fp8_f32(v2, v3, r8, 1);
      *(uint32_t*)(Y1f8 + (size_t)(r0 + rl) * 4096 + m0 + mq * 4) = (uint32_t)r8;
    }
  }
}

// ---------------- MFMA projection GEMM (counted-vmcnt K-loop) ----------------
// MODE 0 (RU): s=sigmoid; Xbf/Xf8 rows 2..65 = r*hx, Ubuf = u, Ht slot0
//              cols 2..65 = bf16(r*hx) transposed.
// MODE 1 (CF): out = u*hx + (1-u)*tanh(...).
template <int MODE>
__global__ __launch_bounds__(256, 4) void proj_mfma(
    const ushort_t* __restrict__ Ht_c, const ushort_t* __restrict__ Wt,
    const float* __restrict__ bias, const float* __restrict__ hx,
    ushort_t* __restrict__ Xbf, uint8_t* __restrict__ Xf8,
    ushort_t* __restrict__ Ubuf, ushort_t* __restrict__ HtW,
    float* __restrict__ out) {
  __shared__ ushort_t smem[16640];
  const int tid = threadIdx.x;
  const int l = tid & 63, w = tid >> 6;
  const int wr = w >> 1, wc = w & 1;
  const int lr = l & 15, lk = l >> 4;
  const int bb = blockIdx.x >> 4;
  const int n0 = (blockIdx.x & 15) * 128;
  const size_t m0 = (size_t)bb * 2048 + n0;

  f32x4 acc[4][4];
  const f32x4 zero = {0.f, 0.f, 0.f, 0.f};
#pragma unroll
  for (int mi = 0; mi < 4; mi++)
#pragma unroll
    for (int ni = 0; ni < 4; ni++) acc[mi][ni] = zero;

  const int srow = tid >> 2;
  const int kcol = ((tid & 3) ^ ((tid >> 3) & 3)) * 8;
  const ushort_t* pA = Ht_c + (m0 + srow) * KP + kcol;
  const ushort_t* pB = Wt + (size_t)srow * KP + kcol;
  const int so = (lk ^ ((lr >> 1) & 3)) * 8;

#define STAGEP(KT, BB)                                                         \
  {                                                                            \
    const int kp_ = (KT) * 32;                                                 \
    gl_lds16(pA + kp_, (void*)&smem[(BB) + tid * 8]);                          \
    gl_lds16(pA + (size_t)64 * KP + kp_, (void*)&smem[(BB) + 2048 + tid * 8]); \
    gl_lds16(pB + kp_, (void*)&smem[(BB) + 4096 + tid * 8]);                   \
    gl_lds16(pB + (size_t)64 * KP + kp_, (void*)&smem[(BB) + 6144 + tid * 8]); \
  }

#define COMPUTEP(BB)                                                           \
  {                                                                            \
    bf16x8 af[4], bfv[4];                                                      \
    _Pragma("unroll")                                                          \
    for (int i = 0; i < 4; i++)                                                \
      af[i] = *(const bf16x8*)&smem[(BB) + (wr * 64 + i * 16 + lr) * 32 + so]; \
    _Pragma("unroll")                                                          \
    for (int i = 0; i < 4; i++)                                                \
      bfv[i] = *(const bf16x8*)&smem[(BB) + 4096 + (wc * 64 + i * 16 + lr) * 32 + so]; \
    _Pragma("unroll")                                                          \
    for (int mi = 0; mi < 4; mi++)                                             \
      _Pragma("unroll")                                                        \
      for (int ni = 0; ni < 4; ni++)                                           \
        acc[mi][ni] = __builtin_amdgcn_mfma_f32_16x16x32_bf16(af[mi], bfv[ni], \
                                                              acc[mi][ni], 0, 0, 0); \
  }

  STAGEP(0, 0);
#pragma unroll 1
  for (int kt = 0; kt < 11; ++kt) {
    if (kt + 1 < 11) {
      STAGEP(kt + 1, ((kt + 1) & 1) * 8192);
      asm volatile("s_waitcnt vmcnt(4)" ::: "memory");
    } else {
      asm volatile("s_waitcnt vmcnt(0)" ::: "memory");
    }
    __builtin_amdgcn_s_barrier();
    __builtin_amdgcn_sched_barrier(0);
    COMPUTEP((kt & 1) * 8192);
    __builtin_amdgcn_s_barrier();
  }

#undef STAGEP
#undef COMPUTEP

  // activation into transposed LDS tile sTile[o][m]
#pragma unroll
  for (int mi = 0; mi < 4; mi++) {
#pragma unroll
    for (int ni = 0; ni < 4; ni++) {
      const int rl0 = wr * 64 + mi * 16 + lk * 4;
      const int o = wc * 64 + ni * 16 + lr;
      float bv = (MODE == 0 || o < 64) ? bias[o] : 0.f;
#pragma unroll
      for (int j = 0; j < 4; j++) {
        float v = acc[mi][ni][j] + bv;
        float s;
        if (MODE == 0) s = 1.f / (1.f + expf(-v));
        else           s = tanhf(v);
        smem[o * 130 + rl0 + j] = f2bf(s);
      }
    }
  }
  __syncthreads();

  if (MODE == 0) {
    // pass 1: o<64 -> smem = r*hx (hx read coalesced); o>=64 -> Ubuf = u
#pragma unroll 4
    for (int j2 = 0; j2 < 64; ++j2) {
      int idx = j2 * 256 + tid;
      int o = idx >> 7, m = idx & 127;
      ushort_t sv = smem[o * 130 + m];
      if (o < 64) {
        float p = bf2f(sv) * hx[((size_t)bb * 64 + o) * 2048 + n0 + m];
        smem[o * 130 + m] = f2bf(p);
      } else {
        Ubuf[((size_t)bb * 64 + (o - 64)) * 2048 + n0 + m] = sv;
      }
    }
    __syncthreads();
    // pass 2: Xbf (ushort4) + Xf8 (dword) rows, coalesced
#pragma unroll 2
    for (int j2 = 0; j2 < 8; ++j2) {
      int idx = j2 * 256 + tid;
      int o = idx >> 5, m4 = (idx & 31) * 4;
      ushort_t s0 = smem[o * 130 + m4 + 0], s1 = smem[o * 130 + m4 + 1];
      ushort_t s2 = smem[o * 130 + m4 + 2], s3 = smem[o * 130 + m4 + 3];
      ushort4 pk4; pk4.x = s0; pk4.y = s1; pk4.z = s2; pk4.w = s3;
      *(ushort4*)&Xbf[((size_t)bb * 66 + 2 + o) * 2048 + n0 + m4] = pk4;
      int r8 = __builtin_amdgcn_cvt_pk_fp8_f32(bf2f(s0), bf2f(s1), 0, 0);
      r8 = __builtin_amdgcn_cvt_pk_fp8_f32(bf2f(s2), bf2f(s3), r8, 1);
      *(uint32_t*)(Xf8 + ((size_t)bb * 66 + 2 + o) * 2048 + n0 + m4) = (uint32_t)r8;
    }
    // pass 3: Ht slot0 cols 2..65 transposed, dword-packed (o even pairs)
#pragma unroll 2
    for (int j2 = 0; j2 < 16; ++j2) {
      int idx = j2 * 256 + tid;
      int m = idx >> 5, po = idx & 31;
      int o = po * 2;
      uint32_t pk = (uint32_t)smem[o * 130 + m] |
                    ((uint32_t)smem[(o + 1) * 130 + m] << 16);
      *(uint32_t*)&HtW[((size_t)bb * 2048 + n0 + m) * KP + 2 + o] = pk;
    }
  } else {
#pragma unroll 4
    for (int j2 = 0; j2 < 32; ++j2) {
      int idx = j2 * 256 + tid;
      int o = idx >> 7, m = idx & 127;
      float Cv = bf2f(smem[o * 130 + m]);
      int n = n0 + m;
      size_t oi = ((size_t)bb * 64 + o) * 2048 + n;
      float u = bf2f(Ubuf[oi]);
      out[oi] = u * hx[oi] + (1.f - u) * Cv;
    }
  }
}

// ---------------- launcher ----------------

extern "C" void kernel_launch(void* const* d_in, const int* in_sizes, int n_in,
                              void* d_out, int out_size, void* d_ws, size_t ws_size,
                              hipStream_t stream) {
  (void)in_sizes; (void)n_in; (void)out_size; (void)ws_size;
  const float* inputs = (const float*)d_in[0];
  const float* hx     = (const float*)d_in[1];
  const float* s0     = (const float*)d_in[2];
  const float* s1     = (const float*)d_in[3];
  const float* W_ru   = (const float*)d_in[4];
  const float* b_ru   = (const float*)d_in[5];
  const float* W_c    = (const float*)d_in[6];
  const float* b_c    = (const float*)d_in[7];
  float* out = (float*)d_out;

  char* p = (char*)d_ws;
  uint8_t*  Abf8 = (uint8_t*)p;  p += (size_t)4096 * 2048;        //  8.39 MB
  ushort_t* Xbf  = (ushort_t*)p; p += (size_t)4224 * 2048 * 2;    // 17.30 MB
  uint8_t*  Xf8  = (uint8_t*)p;  p += (size_t)4224 * 2048;        //  8.65 MB
  uint8_t*  Y1f8 = (uint8_t*)p;  p += (size_t)4224 * 4096;        // 17.30 MB
  ushort_t* Ht   = (ushort_t*)p; p += (size_t)MROWS * KP * 2;     // 92.27 MB
  ushort_t* Ubuf = (ushort_t*)p; p += (size_t)64 * 64 * 2048 * 2; // 16.78 MB
  ushort_t* Wtru = (ushort_t*)p; p += (size_t)128 * KP * 2;       // 90 KB
  ushort_t* Wtc  = (ushort_t*)p; p += (size_t)128 * KP * 2;       // 90 KB

  // fused prep: casts + build_X + pack_W + trans_slot0 (all independent)
  k_prep<<<6464, 256, 0, stream>>>(inputs, hx, s0, s1, W_ru, W_c,
                                   Abf8, Xbf, Xf8, Wtru, Wtc, Ht);

  dim3 g(33, 32);
  // conv 1
  gemm_bt<0><<<g, 256, 0, stream>>>(Xf8, 2048, Abf8, nullptr, Y1f8, Ht);
  gemm_bt<1><<<g, 256, 0, stream>>>(Y1f8, 4096, Abf8, Xbf, nullptr, Ht);
  proj_mfma<0><<<1024, 256, 0, stream>>>(Ht, Wtru, b_ru, hx, Xbf, Xf8, Ubuf, Ht, nullptr);
  // conv 2 (slot0 cols 0,1 persist; cols 2..65 written by proj_mfma<0>)
  gemm_bt<0><<<g, 256, 0, stream>>>(Xf8, 2048, Abf8, nullptr, Y1f8, Ht);
  gemm_bt<1><<<g, 256, 0, stream>>>(Y1f8, 4096, Abf8, Xbf, nullptr, Ht);
  proj_mfma<1><<<1024, 256, 0, stream>>>(Ht, Wtc, b_c, hx, nullptr, nullptr, Ubuf, nullptr, out);
}